// Round 1
// baseline (450.178 us; speedup 1.0000x reference)
//
#include <hip/hip_runtime.h>
#include <cstdint>
#include <cstddef>

// Problem constants (B,S,E,H)=(2,2048,2048,16), D=128, RD=128 (full-rotary)
#define Bd 2
#define Sd 2048
#define Ed 2048
#define Hd 16
#define Dd 128
#define N3E 6144
#define ATT_SCALE 0.08838834764831845f   // 1/sqrt(128)

typedef short bf16x8 __attribute__((ext_vector_type(8)));
typedef float f32x4 __attribute__((ext_vector_type(4)));
typedef float f32x16 __attribute__((ext_vector_type(16)));

__device__ __forceinline__ float bf2f(unsigned short u) {
    union { unsigned int u; float f; } c;
    c.u = ((unsigned int)u) << 16;
    return c.f;
}
__device__ __forceinline__ unsigned short f2bf(float f) {
    union { float f; unsigned int u; } c;
    c.f = f;
    unsigned int x = c.u;
    x += 0x7FFFu + ((x >> 16) & 1u);   // RTNE (finite values only)
    return (unsigned short)(x >> 16);
}

__device__ __forceinline__ void gl2lds16(const void* g, void* l) {
    __builtin_amdgcn_global_load_lds(
        (const __attribute__((address_space(1))) void*)g,
        (__attribute__((address_space(3))) void*)l, 16, 0, 0);
}

// ---------------- fp32 -> bf16 convert (x, wqkv_w, out_w in one launch) ----
__global__ void cvt_all(const float* __restrict__ x,
                        const float* __restrict__ w1,
                        const float* __restrict__ w2,
                        unsigned short* __restrict__ ox,
                        unsigned short* __restrict__ o1,
                        unsigned short* __restrict__ o2) {
    int i = (blockIdx.x * 256 + threadIdx.x) * 4;
    const float* s;
    unsigned short* d;
    int off;
    if (i < 8388608) { s = x; d = ox; off = i; }
    else if (i < 20971520) { s = w1; d = o1; off = i - 8388608; }
    else { s = w2; d = o2; off = i - 20971520; }
    const float4 v = *(const float4*)(s + off);
    d[off + 0] = f2bf(v.x);
    d[off + 1] = f2bf(v.y);
    d[off + 2] = f2bf(v.z);
    d[off + 3] = f2bf(v.w);
}

// ---------------- bf16 MFMA GEMM, C = A * B^T + bias ----------------
// 8-phase-style pipelined template (T2+T3+T4+T5):
//   BM=256, BN=128, BK=64, 512 threads = 8 waves (4M x 2N), 64x64 C per wave.
//   LDS: triple-buffered ring, slot = 48 KB (A 256x64 + B 128x64 bf16),
//        3 slots = 144 KB -> 1 block/CU. Compute slot t%3 while tile t+2
//        stages into (t+2)%3 -> prefetch distance 2 K-tiles; steady-state
//        wait is vmcnt(6) (= tile t+2's 6 loads in flight), never 0 in loop.
//   Per K-tile: 2 phases x {stage 3 gl2lds || ds_read frags -> s_barrier ->
//        16 MFMA in setprio(1) -> s_barrier}. Raw s_barrier (not
//        __syncthreads) so the compiler does NOT drain vmcnt at barriers.
//   XOR-chunk LDS swizzle (8x16B chunks/row, chunk ^= row&7) with
//        pre-swizzled global source (gl2lds dst must stay linear).
// MODE 0: fp32 row-major out (o0), Ndim cols.
// MODE 1: fused QKV epilogue per 128-col tile (= one head): q/k RoPE ->
//        [B,H,S,D]; v transpose -> [B,H,D,S]. Epilogue tile 256x130 bf16
//        (66.5 KB) unions into the A-ring (96 KB).
template <int MODE>
__global__ __launch_bounds__(512, 2) void gemm_bt(
    const unsigned short* __restrict__ A,
    const unsigned short* __restrict__ Bm,
    const float* __restrict__ bias,
    void* __restrict__ o0, void* __restrict__ o1,
    void* __restrict__ o2, int Ndim, int K) {
    __shared__ __align__(16) unsigned short As[3 * 256 * 64];  // 96 KB ring
    __shared__ __align__(16) unsigned short Bs[3 * 128 * 64];  // 48 KB ring

    const int tid = threadIdx.x;
    const int lane = tid & 63;
    const int wave = tid >> 6;   // 0..7
    const int quad = lane >> 4;
    const int l16 = lane & 15;
    const int wr = wave >> 1;    // 0..3 (M): rows wr*64..+64
    const int wc = wave & 1;     // 0..1 (N): cols wc*64..+64

    const int n0 = blockIdx.x * 128;
    const int m0 = blockIdx.y * 256;
    const unsigned short* Ab = A + (size_t)m0 * K;
    const unsigned short* Bb = Bm + (size_t)n0 * K;
    const int NT = K >> 6;   // 32 for K=2048

    const f32x4 fzero = {0.f, 0.f, 0.f, 0.f};
    f32x4 acc[4][4];
#pragma unroll
    for (int i = 0; i < 4; i++)
#pragma unroll
        for (int j = 0; j < 4; j++) acc[i][j] = fzero;

    // staging: per K-tile 6 gl2lds/thread (A: 4, B: 2), 16B each,
    // pre-swizzled global source so linear LDS dst ends up chunk-XOR'd.
    auto stA = [&](int slot, int k0, int half) {
#pragma unroll
        for (int it = 0; it < 2; ++it) {
            int L = (half * 2 + it) * 512 + tid;   // 0..2047
            int row = L >> 3;                       // 0..255
            int cs = L & 7;
            int gc = cs ^ (row & 7);
            gl2lds16(Ab + (size_t)row * K + k0 + gc * 8,
                     (void*)(As + slot * 16384 + L * 8));
        }
    };
    auto stB = [&](int slot, int k0, int half) {
        int L = half * 512 + tid;                   // 0..1023
        int row = L >> 3;                           // 0..127
        int cs = L & 7;
        int gc = cs ^ (row & 7);
        gl2lds16(Bb + (size_t)row * K + k0 + gc * 8,
                 (void*)(Bs + slot * 8192 + L * 8));
    };

    // prologue: stage tiles 0 and 1; wait for tile 0 (6 of tile 1 in flight)
    stA(0, 0, 0); stB(0, 0, 0); stA(0, 0, 1); stB(0, 0, 1);
    stA(1, 64, 0); stB(1, 64, 0); stA(1, 64, 1); stB(1, 64, 1);
    asm volatile("s_waitcnt vmcnt(6)" ::: "memory");
    __builtin_amdgcn_s_barrier();

    for (int t = 0; t < NT; ++t) {
        const int sc = t % 3;
        const int sp = (t + 2) % 3;
        const int k2 = (t + 2) << 6;
        const unsigned short* Asl = As + sc * 16384;
        const unsigned short* Bsl = Bs + sc * 8192;
        const bool pf = (t + 2 < NT);

        // ---- phase A: stage half 0 of tile t+2; B all 8 frags + A i=0,1 ----
        if (pf) { stA(sp, k2, 0); stB(sp, k2, 0); }
        bf16x8 bfr[4][2], af0[2][2];
#pragma unroll
        for (int j = 0; j < 4; j++) {
            int row = wc * 64 + j * 16 + l16;
#pragma unroll
            for (int kk = 0; kk < 2; kk++)
                bfr[j][kk] = *(const bf16x8*)(
                    Bsl + row * 64 + (((kk * 4 + quad) ^ (row & 7))) * 8);
        }
#pragma unroll
        for (int i = 0; i < 2; i++) {
            int row = wr * 64 + i * 16 + l16;
#pragma unroll
            for (int kk = 0; kk < 2; kk++)
                af0[i][kk] = *(const bf16x8*)(
                    Asl + row * 64 + (((kk * 4 + quad) ^ (row & 7))) * 8);
        }
        __builtin_amdgcn_s_barrier();
        __builtin_amdgcn_s_setprio(1);
#pragma unroll
        for (int kk = 0; kk < 2; kk++)
#pragma unroll
            for (int i = 0; i < 2; i++)
#pragma unroll
                for (int j = 0; j < 4; j++)
                    acc[i][j] = __builtin_amdgcn_mfma_f32_16x16x32_bf16(
                        af0[i][kk], bfr[j][kk], acc[i][j], 0, 0, 0);
        __builtin_amdgcn_s_setprio(0);
        __builtin_amdgcn_s_barrier();

        // ---- phase B: stage half 1 of tile t+2; A i=2,3 (B held in regs) ----
        if (pf) { stA(sp, k2, 1); stB(sp, k2, 1); }
        bf16x8 af1[2][2];
#pragma unroll
        for (int i = 0; i < 2; i++) {
            int row = wr * 64 + (i + 2) * 16 + l16;
#pragma unroll
            for (int kk = 0; kk < 2; kk++)
                af1[i][kk] = *(const bf16x8*)(
                    Asl + row * 64 + (((kk * 4 + quad) ^ (row & 7))) * 8);
        }
        __builtin_amdgcn_s_barrier();
        __builtin_amdgcn_s_setprio(1);
#pragma unroll
        for (int kk = 0; kk < 2; kk++)
#pragma unroll
            for (int i = 0; i < 2; i++)
#pragma unroll
                for (int j = 0; j < 4; j++)
                    acc[i + 2][j] = __builtin_amdgcn_mfma_f32_16x16x32_bf16(
                        af1[i][kk], bfr[j][kk], acc[i + 2][j], 0, 0, 0);
        __builtin_amdgcn_s_setprio(0);
        // iteration end: tile t+1 must be landed for everyone after barrier.
        // Outstanding allowed = tile t+2's 6 loads (counted, never 0 until
        // the last two iterations' natural drain).
        if (pf) asm volatile("s_waitcnt vmcnt(6)" ::: "memory");
        else    asm volatile("s_waitcnt vmcnt(0)" ::: "memory");
        __builtin_amdgcn_s_barrier();
    }

    if (MODE == 0) {
#pragma unroll
        for (int j = 0; j < 4; j++) {
            int col = n0 + wc * 64 + j * 16 + l16;
            float bv = bias[col];
#pragma unroll
            for (int i = 0; i < 4; i++) {
                int rbase = m0 + wr * 64 + i * 16 + quad * 4;
#pragma unroll
                for (int r = 0; r < 4; r++)
                    ((float*)o0)[(size_t)(rbase + r) * Ndim + col] =
                        acc[i][j][r] + bv;
            }
        }
    } else {
        // ---- fused QKV epilogue (tile = 256 rows x 128 cols = one head) ----
        // last loop iteration ended with a full barrier and vmcnt(0); all
        // LDS reads are consumed -> safe to overwrite the ring as U.
        unsigned short* U = As;   // 256 x 130 bf16 = 66,560 B <= 96 KB
#pragma unroll
        for (int j = 0; j < 4; j++) {
            int coll = wc * 64 + j * 16 + l16;   // tile-local col = d
            float bv = bias[n0 + coll];
#pragma unroll
            for (int i = 0; i < 4; i++) {
                int rl = wr * 64 + i * 16 + quad * 4;
#pragma unroll
                for (int r = 0; r < 4; r++)
                    U[(rl + r) * 130 + coll] = f2bf(acc[i][j][r] + bv);
            }
        }
        __syncthreads();

        const int ch = n0 >> 7;         // 0..47
        const int c = ch >> 4;          // 0=q 1=k 2=v
        const int h = ch & 15;
        const int bb = m0 >> 11;        // batch (tile never crosses: 2048%256==0)
        const int s0 = m0 & 2047;

        if (c < 2) {
            unsigned short* dstq = (unsigned short*)(c == 0 ? o0 : o1);
            const size_t hb = ((size_t)(bb * Hd + h)) * Sd;
#pragma unroll
            for (int it = 0; it < 16; ++it) {
                int lin = it * 512 + tid;        // 256 rows x 32 d-pairs
                int row = lin >> 5, p = lin & 31;
                int s = s0 + row;
                unsigned int lo = *(const unsigned int*)(U + row * 130 + 2 * p);
                unsigned int hi =
                    *(const unsigned int*)(U + row * 130 + 64 + 2 * p);
                float v1a = bf2f((unsigned short)lo), v1b = bf2f(lo >> 16);
                float v2a = bf2f((unsigned short)hi), v2b = bf2f(hi >> 16);
                // theta_j = s * 10000^(-j/64),  j = 2p, 2p+1
                float fa = (float)s * __expf(-(float)(2 * p) *
                                             (9.210340371976184f / 64.0f));
                float fb = (float)s * __expf(-(float)(2 * p + 1) *
                                             (9.210340371976184f / 64.0f));
                float sna, csa, snb, csb;
                __sincosf(fa, &sna, &csa);
                __sincosf(fb, &snb, &csb);
                ushort2 r1, r2;
                r1.x = f2bf(v1a * csa - v2a * sna);
                r1.y = f2bf(v1b * csb - v2b * snb);
                r2.x = f2bf(v1a * sna + v2a * csa);
                r2.y = f2bf(v1b * snb + v2b * csb);
                unsigned short* dst = dstq + (hb + s) * Dd;
                *(ushort2*)(dst + 2 * p) = r1;
                *(ushort2*)(dst + 64 + 2 * p) = r2;
            }
        } else {
            unsigned short* dstv = (unsigned short*)o2;
            const size_t hb = ((size_t)(bb * Hd + h)) * Dd;
#pragma unroll
            for (int it = 0; it < 16; ++it) {
                int lin = it * 512 + tid;        // 128 d x 64 s-chunks
                int d = lin >> 6, sc2 = lin & 63;
                int s4 = sc2 * 4;
                ushort4 pk;
                pk.x = U[(s4 + 0) * 130 + d];
                pk.y = U[(s4 + 1) * 130 + d];
                pk.z = U[(s4 + 2) * 130 + d];
                pk.w = U[(s4 + 3) * 130 + d];
                *(ushort4*)(dstv + (hb + d) * Sd + s0 + s4) = pk;
            }
        }
    }
}

// ---------------- flash attention (causal, online softmax) ----------------
// 32x32x16 MFMA, BM=128 (32 q/wave), BN=64. S^T = K*Q^T with Q in registers;
// O^T = Vt*P^T. C/D col = q = lane&31 -> softmax and alpha/li rescale fully
// lane-local (1 shfl_xor per reduction). Ps is 128x64 with XOR-chunk swizzle
// so every ds access is naturally aligned, and an explicit barrier between
// P-store and PV-read.
// 32x32 layouts (verified m74/m101): A/B [n=lane&31][k=(lane>>5)*8+j];
// C/D col=lane&31, row=(reg&3)+8*(reg>>2)+4*(lane>>5).
__global__ __launch_bounds__(256, 2) void flash_attn(
    const unsigned short* __restrict__ q, const unsigned short* __restrict__ k,
    const unsigned short* __restrict__ vt, unsigned short* __restrict__ ctx) {
    __shared__ __align__(16) unsigned short Ks[64 * 128];   // 16 KB [t][d], 16 chunks/row, xor row&15
    __shared__ __align__(16) unsigned short Vts[128 * 64];  // 16 KB [d][t], 8 chunks/row, xor row&7
    __shared__ __align__(16) unsigned short Ps[128 * 64];   // 16 KB [q][t], 8 chunks/row, xor row&7

    const int tid = threadIdx.x;
    const int lane = tid & 63;
    const int wave = tid >> 6;
    const int l32 = lane & 31;
    const int half = lane >> 5;

    // qi pairing: CU gets blocks y and y+8 (round-robin, 512 blocks / 256 CU)
    // -> qi {15-y, y}: per-CU tile count constant (34).
    const int yy = blockIdx.y;
    const int qi = (yy < 8) ? 15 - yy : yy - 8;
    const int bh = blockIdx.x;
    const int q0 = qi * 128;
    const int qg = q0 + wave * 32 + l32;        // this lane's global q row
    const int prow = wave * 32 + l32;           // P row (q local)
    const int psw = prow & 7;                   // P swizzle key

    const unsigned short* kb = k + (size_t)bh * Sd * Dd;
    const unsigned short* vtb = vt + (size_t)bh * Dd * Sd;

    // Q fragments straight from global: lane owns row qg, frag ks covers
    // d = ks*16 + half*8 + {0..7}  (B-operand layout), 8 x 16B loads.
    bf16x8 aq[8];
    {
        const unsigned short* qrow = q + ((size_t)bh * Sd + qg) * Dd;
#pragma unroll
        for (int ks = 0; ks < 8; ks++)
            aq[ks] = *(const bf16x8*)(qrow + ks * 16 + half * 8);
    }

    f32x16 o[4];   // O^T: d-block db: row d = db*32+(r&3)+8*(r>>2)+4*half, col q=l32
#pragma unroll
    for (int db = 0; db < 4; db++)
#pragma unroll
        for (int r = 0; r < 16; r++) o[db][r] = 0.f;
    float mi = -3.0e38f, li = 0.f;

    const int tmax = q0 + 64;
    for (int t0 = 0; t0 <= tmax; t0 += 64) {
        // stage K [64t][128d] and Vt [128d][64t], 1024 16B-chunks each
#pragma unroll
        for (int it = 0; it < 4; ++it) {
            int L = it * 256 + tid;
            int rk = L >> 4;
            int ck = L & 15;
            int gk = ck ^ (rk & 15);
            gl2lds16(kb + (size_t)(t0 + rk) * Dd + gk * 8, (void*)(Ks + L * 8));
            int rv = L >> 3;
            int cv = L & 7;
            int gv = cv ^ (rv & 7);
            gl2lds16(vtb + (size_t)rv * Sd + t0 + gv * 8, (void*)(Vts + L * 8));
        }
        __syncthreads();

        // S^T = K * Q^T : 2 t-blocks of 32, contraction d=128 (8 ksteps)
        f32x16 sa[2];
#pragma unroll
        for (int b2 = 0; b2 < 2; b2++)
#pragma unroll
            for (int r = 0; r < 16; r++) sa[b2][r] = 0.f;
#pragma unroll
        for (int ks = 0; ks < 8; ks++) {
            int cd = ks * 2 + half;
#pragma unroll
            for (int b2 = 0; b2 < 2; b2++) {
                int row = b2 * 32 + l32;
                bf16x8 ak = *(const bf16x8*)(Ks + row * 128 +
                                             (cd ^ (row & 15)) * 8);
                sa[b2] = __builtin_amdgcn_mfma_f32_32x32x16_bf16(ak, aq[ks],
                                                                 sa[b2], 0, 0, 0);
            }
        }

        // scale + causal mask; per-lane row max over 32 reg values + 1 shfl
        float mx = -3.0e38f;
#pragma unroll
        for (int b2 = 0; b2 < 2; b2++)
#pragma unroll
            for (int r = 0; r < 16; r++) {
                float v = sa[b2][r] * ATT_SCALE;
                int tg = t0 + b2 * 32 + (r & 3) + 8 * (r >> 2) + 4 * half;
                if (tg > qg) v = -3.0e38f;
                sa[b2][r] = v;
                mx = fmaxf(mx, v);
            }
        mx = fmaxf(mx, __shfl_xor(mx, 32, 64));
        const float mnew = fmaxf(mi, mx);
        const float alpha = __expf(mi - mnew);
        float rs = 0.f;
#pragma unroll
        for (int b2 = 0; b2 < 2; b2++)
#pragma unroll
            for (int r = 0; r < 16; r++) {
                float pp = __expf(sa[b2][r] - mnew);
                sa[b2][r] = pp;
                rs += pp;
            }
        rs += __shfl_xor(rs, 32, 64);
        li = li * alpha + rs;
        mi = mnew;

        // rescale O (fully in-lane: O^T col q == softmax lane q)
#pragma unroll
        for (int db = 0; db < 4; db++)
#pragma unroll
            for (int r = 0; r < 16; r++) o[db][r] *= alpha;

        // P store: row prow holds P[q][t] in t-order, 8 chunks of 8 ushorts,
        // chunk XOR-swizzled by prow&7. reg (b2,g) -> t = b2*32+8g+4*half+{0..3}
        // -> chunk b2*4+g, within-chunk half*4: 8B-aligned ds_write_b64.
#pragma unroll
        for (int b2 = 0; b2 < 2; b2++)
#pragma unroll
            for (int g = 0; g < 4; g++) {
                ushort4 pk;
                pk.x = f2bf(sa[b2][g * 4 + 0]);
                pk.y = f2bf(sa[b2][g * 4 + 1]);
                pk.z = f2bf(sa[b2][g * 4 + 2]);
                pk.w = f2bf(sa[b2][g * 4 + 3]);
                *(ushort4*)(Ps + prow * 64 + ((b2 * 4 + g) ^ psw) * 8 +
                            half * 4) = pk;
            }
        __syncthreads();  // P visible (and guards vs any cross-lane timing)

        // O^T += Vt * P^T : 4 d-blocks, contraction t=64 (4 ksteps)
        // bp chunk = kk*2+half -> t = kk*16+half*8+{0..7}: 16B-aligned b128.
#pragma unroll
        for (int kk = 0; kk < 4; kk++) {
            bf16x8 bp = *(const bf16x8*)(Ps + prow * 64 +
                                         ((kk * 2 + half) ^ psw) * 8);
#pragma unroll
            for (int db = 0; db < 4; db++) {
                int row = db * 32 + l32;
                bf16x8 av = *(const bf16x8*)(
                    Vts + row * 64 + ((kk * 2 + half) ^ (row & 7)) * 8);
                o[db] = __builtin_amdgcn_mfma_f32_32x32x16_bf16(av, bp, o[db],
                                                                0, 0, 0);
            }
        }
        __syncthreads();  // protect Ks/Vts/Ps before next-tile staging
    }

    // epilogue: ctx[b, qg, h*128+d] = O^T[d][qg] / li  (bf16, ushort4 groups)
    const int b = bh >> 4;
    const int h = bh & 15;
    const float inv = 1.0f / li;
    unsigned short* dst = ctx + ((size_t)(b * Sd + qg)) * Ed + h * Dd;
#pragma unroll
    for (int db = 0; db < 4; db++)
#pragma unroll
        for (int g = 0; g < 4; g++) {
            ushort4 pk;
            pk.x = f2bf(o[db][g * 4 + 0] * inv);
            pk.y = f2bf(o[db][g * 4 + 1] * inv);
            pk.z = f2bf(o[db][g * 4 + 2] * inv);
            pk.w = f2bf(o[db][g * 4 + 3] * inv);
            *(ushort4*)(dst + db * 32 + g * 8 + half * 4) = pk;
        }
}

extern "C" void kernel_launch(void* const* d_in, const int* in_sizes, int n_in,
                              void* d_out, int out_size, void* d_ws,
                              size_t ws_size, hipStream_t stream) {
    const float* x = (const float*)d_in[0];
    const float* wqkv_w = (const float*)d_in[1];
    const float* wqkv_b = (const float*)d_in[2];
    const float* out_w = (const float*)d_in[3];
    const float* out_b = (const float*)d_in[4];
    float* out = (float*)d_out;

    // workspace layout (bytes); total 100,663,296 (96 MiB)
    char* ws = (char*)d_ws;
    unsigned short* xb    = (unsigned short*)(ws + 0);         // 16 MiB, dead after QKV GEMM
    unsigned short* wqkvb = (unsigned short*)(ws + 16777216);  // 24 MiB
    unsigned short* owb   = (unsigned short*)(ws + 41943040);  // 8 MiB
    unsigned short* qb    = (unsigned short*)(ws + 50331648);  // 16 MiB [B,H,S,D]
    unsigned short* kb    = (unsigned short*)(ws + 67108864);  // 16 MiB [B,H,S,D]
    unsigned short* vtb   = (unsigned short*)(ws + 83886080);  // 16 MiB [B,H,D,S]
    unsigned short* ctx   = (unsigned short*)(ws + 0);         // alias xb (dead)

    cvt_all<<<24576, 256, 0, stream>>>(x, wqkv_w, out_w, xb, wqkvb, owb);
    // qkv = x @ wqkv_w^T + b, fused RoPE (q,k) + V-transpose in epilogue
    // BM=256 x BN=128: grid (48,16) = 768 blocks = exactly 3 rounds @ 1/CU
    gemm_bt<1><<<dim3(48, 16), 512, 0, stream>>>(xb, wqkvb, wqkv_b, qb, kb, vtb,
                                                 N3E, Ed);
    flash_attn<<<dim3(32, 16), 256, 0, stream>>>(qb, kb, vtb, ctx);
    // out = ctx @ out_w^T + b  (fp32); grid (16,16) = 256 blocks = 1 round
    gemm_bt<0><<<dim3(16, 16), 512, 0, stream>>>(ctx, owb, out_b, out, nullptr,
                                                 nullptr, Ed, Ed);
}

// Round 3
// 345.051 us; speedup vs baseline: 1.3047x; 1.3047x over previous
//
#include <hip/hip_runtime.h>
#include <cstdint>
#include <cstddef>

// Problem constants (B,S,E,H)=(2,2048,2048,16), D=128, RD=128 (full-rotary)
#define Bd 2
#define Sd 2048
#define Ed 2048
#define Hd 16
#define Dd 128
#define N3E 6144
#define ATT_SCALE 0.08838834764831845f   // 1/sqrt(128)

typedef short bf16x8 __attribute__((ext_vector_type(8)));
typedef float f32x4 __attribute__((ext_vector_type(4)));
typedef float f32x16 __attribute__((ext_vector_type(16)));

__device__ __forceinline__ float bf2f(unsigned short u) {
    union { unsigned int u; float f; } c;
    c.u = ((unsigned int)u) << 16;
    return c.f;
}
__device__ __forceinline__ unsigned short f2bf(float f) {
    union { float f; unsigned int u; } c;
    c.f = f;
    unsigned int x = c.u;
    x += 0x7FFFu + ((x >> 16) & 1u);   // RTNE (finite values only)
    return (unsigned short)(x >> 16);
}

__device__ __forceinline__ void gl2lds16(const void* g, void* l) {
    __builtin_amdgcn_global_load_lds(
        (const __attribute__((address_space(1))) void*)g,
        (__attribute__((address_space(3))) void*)l, 16, 0, 0);
}

// ---------------- fp32 -> bf16 convert (x, wqkv_w, out_w in one launch) ----
__global__ void cvt_all(const float* __restrict__ x,
                        const float* __restrict__ w1,
                        const float* __restrict__ w2,
                        unsigned short* __restrict__ ox,
                        unsigned short* __restrict__ o1,
                        unsigned short* __restrict__ o2) {
    int i = (blockIdx.x * 256 + threadIdx.x) * 4;
    const float* s;
    unsigned short* d;
    int off;
    if (i < 8388608) { s = x; d = ox; off = i; }
    else if (i < 20971520) { s = w1; d = o1; off = i - 8388608; }
    else { s = w2; d = o2; off = i - 20971520; }
    const float4 v = *(const float4*)(s + off);
    d[off + 0] = f2bf(v.x);
    d[off + 1] = f2bf(v.y);
    d[off + 2] = f2bf(v.z);
    d[off + 3] = f2bf(v.w);
}

// ---------------- bf16 MFMA GEMM, C = A * B^T + bias ----------------
// (proven 927-TF structure: 128x128 tile, BK=64, 4 waves, 33 KB LDS ->
//  4 blocks/CU; inter-block overlap hides the per-tile drain.)
// A: M x K (K contig), Bm: N x K (K contig). XOR-swizzled LDS (8 chunks/row
// of 16B) so frag ds_read_b128 is 2-way (free).
// MODE 0: fp32 row-major out (o0), Ndim cols.
// MODE 1: fused QKV epilogue. Each 128-col tile = one head (D=128) of q/k/v:
//   tile -> LDS (bf16, stride 130), then q/k: RoPE + store [B,H,S,D];
//   v: transpose via column gather -> [B,H,D,S].
template <int MODE>
__global__ void gemm_bt(const unsigned short* __restrict__ A,
                        const unsigned short* __restrict__ Bm,
                        const float* __restrict__ bias,
                        void* __restrict__ o0, void* __restrict__ o1,
                        void* __restrict__ o2, int Ndim, int K) {
    // union: staging (As 16KB + Bs 16KB) / epilogue tile 128x130 bf16 (33,280B)
    __shared__ __align__(16) unsigned short U[16640];
    unsigned short* As = U;
    unsigned short* Bs = U + 8192;

    const int tid = threadIdx.x;
    const int lane = tid & 63;
    const int wave = tid >> 6;
    const int quad = lane >> 4;
    const int l16 = lane & 15;
    const int wr = wave >> 1;
    const int wc = wave & 1;

    const int n0 = blockIdx.x * 128;
    const int m0 = blockIdx.y * 128;

    const unsigned short* Ab = A + (size_t)m0 * K;
    const unsigned short* Bb = Bm + (size_t)n0 * K;

    const f32x4 fzero = {0.f, 0.f, 0.f, 0.f};
    f32x4 acc[4][4];
#pragma unroll
    for (int i = 0; i < 4; i++)
#pragma unroll
        for (int j = 0; j < 4; j++) acc[i][j] = fzero;

    for (int k0 = 0; k0 < K; k0 += 64) {
        __syncthreads();
#pragma unroll
        for (int it = 0; it < 4; ++it) {
            int L = it * 256 + tid;
            int row = L >> 3;
            int cs = L & 7;
            int gc = cs ^ (row & 7);
            gl2lds16(Ab + row * K + k0 + gc * 8, (void*)(As + L * 8));
            gl2lds16(Bb + row * K + k0 + gc * 8, (void*)(Bs + L * 8));
        }
        __syncthreads();
#pragma unroll
        for (int kk = 0; kk < 2; ++kk) {
            bf16x8 af[4], bfr[4];
#pragma unroll
            for (int i = 0; i < 4; i++) {
                int row = wr * 64 + i * 16 + l16;
                int cs = kk * 4 + quad;
                af[i] = *(const bf16x8*)(As + row * 64 + (cs ^ (row & 7)) * 8);
            }
#pragma unroll
            for (int j = 0; j < 4; j++) {
                int row = wc * 64 + j * 16 + l16;
                int cs = kk * 4 + quad;
                bfr[j] = *(const bf16x8*)(Bs + row * 64 + (cs ^ (row & 7)) * 8);
            }
#pragma unroll
            for (int i = 0; i < 4; i++)
#pragma unroll
                for (int j = 0; j < 4; j++)
                    acc[i][j] = __builtin_amdgcn_mfma_f32_16x16x32_bf16(
                        af[i], bfr[j], acc[i][j], 0, 0, 0);
        }
    }

    if (MODE == 0) {
#pragma unroll
        for (int j = 0; j < 4; j++) {
            int col = n0 + wc * 64 + j * 16 + l16;
            float bv = bias[col];
#pragma unroll
            for (int i = 0; i < 4; i++) {
                int rbase = m0 + wr * 64 + i * 16 + quad * 4;
#pragma unroll
                for (int r = 0; r < 4; r++)
                    ((float*)o0)[(size_t)(rbase + r) * Ndim + col] =
                        acc[i][j][r] + bv;
            }
        }
    } else {
        // ---- fused QKV epilogue ----
        __syncthreads();  // all frag reads of As/Bs done before tile overwrite
#pragma unroll
        for (int j = 0; j < 4; j++) {
            int coll = wc * 64 + j * 16 + l16;   // tile-local col = d
            float bv = bias[n0 + coll];
#pragma unroll
            for (int i = 0; i < 4; i++) {
                int rl = wr * 64 + i * 16 + quad * 4;
#pragma unroll
                for (int r = 0; r < 4; r++)
                    U[(rl + r) * 130 + coll] = f2bf(acc[i][j][r] + bv);
            }
        }
        __syncthreads();

        const int ch = n0 >> 7;         // 0..47
        const int c = ch >> 4;          // 0=q 1=k 2=v
        const int h = ch & 15;
        const int bb = m0 >> 11;        // batch (tile never crosses: 2048%128==0)
        const int s0 = m0 & 2047;

        if (c < 2) {
            unsigned short* dstq = (unsigned short*)(c == 0 ? o0 : o1);
            const size_t hb = ((size_t)(bb * Hd + h)) * Sd;
#pragma unroll
            for (int it = 0; it < 16; ++it) {
                int lin = it * 256 + tid;        // 128 rows x 32 d-pairs
                int row = lin >> 5, p = lin & 31;
                int s = s0 + row;
                unsigned int lo = *(const unsigned int*)(U + row * 130 + 2 * p);
                unsigned int hi =
                    *(const unsigned int*)(U + row * 130 + 64 + 2 * p);
                float v1a = bf2f((unsigned short)lo), v1b = bf2f(lo >> 16);
                float v2a = bf2f((unsigned short)hi), v2b = bf2f(hi >> 16);
                // theta_j = s * 10000^(-j/64),  j = 2p, 2p+1
                float fa = (float)s * __expf(-(float)(2 * p) *
                                             (9.210340371976184f / 64.0f));
                float fb = (float)s * __expf(-(float)(2 * p + 1) *
                                             (9.210340371976184f / 64.0f));
                float sna, csa, snb, csb;
                __sincosf(fa, &sna, &csa);
                __sincosf(fb, &snb, &csb);
                ushort2 r1, r2;
                r1.x = f2bf(v1a * csa - v2a * sna);
                r1.y = f2bf(v1b * csb - v2b * snb);
                r2.x = f2bf(v1a * sna + v2a * csa);
                r2.y = f2bf(v1b * snb + v2b * csb);
                unsigned short* dst = dstq + (hb + s) * Dd;
                *(ushort2*)(dst + 2 * p) = r1;
                *(ushort2*)(dst + 64 + 2 * p) = r2;
            }
        } else {
            unsigned short* dstv = (unsigned short*)o2;
            const size_t hb = ((size_t)(bb * Hd + h)) * Dd;
#pragma unroll
            for (int it = 0; it < 16; ++it) {
                int lin = it * 256 + tid;        // 128 d x 32 s-chunks
                int d = lin >> 5, sc = lin & 31;
                int s4 = sc * 4;
                ushort4 pk;
                pk.x = U[(s4 + 0) * 130 + d];
                pk.y = U[(s4 + 1) * 130 + d];
                pk.z = U[(s4 + 2) * 130 + d];
                pk.w = U[(s4 + 3) * 130 + d];
                *(ushort4*)(dstv + (hb + d) * Sd + s0 + s4) = pk;
            }
        }
    }
}

// ---------------- flash attention (causal, online softmax) ----------------
// 32x32x16 MFMA, BM=128 (32 q/wave), BN=64. S^T = K*Q^T with Q in registers;
// O^T = Vt*P^T. C/D col = q = lane&31 -> softmax and alpha/li rescale fully
// lane-local (1 shfl_xor per reduction).
// 2-phase / stage-early: K/V double-buffered (LDS 80 KB, 2 blocks/CU).
// Per tile exactly ONE __syncthreads (top of iter):
//   sync (buf[cur] landed; prev iter's reads of buf[cur^1] done)
//   -> issue next tile's gl2lds into buf[cur^1] (lands during compute,
//      so the next sync's vmcnt(0) drain is ~free)
//   -> QK, softmax, P-store, PV.
// P-store->PV barrier removed: P rows [wave*32, wave*32+32) are written and
// read ONLY by that wave (prow = wave*32 + l32 for both the ds_write and the
// bp ds_read); intra-wave LDS write->read ordering is handled by
// compiler-inserted lgkmcnt waits. Post-PV barrier subsumed by loop-top sync.
// 32x32 layouts (verified m74/m101): A/B [n=lane&31][k=(lane>>5)*8+j];
// C/D col=lane&31, row=(reg&3)+8*(reg>>2)+4*(lane>>5).
__global__ __launch_bounds__(256, 2) void flash_attn(
    const unsigned short* __restrict__ q, const unsigned short* __restrict__ k,
    const unsigned short* __restrict__ vt, unsigned short* __restrict__ ctx) {
    __shared__ __align__(16) unsigned short Ks[2][64 * 128];   // 2x16 KB [t][d], 16 chunks/row, xor row&15
    __shared__ __align__(16) unsigned short Vts[2][128 * 64];  // 2x16 KB [d][t], 8 chunks/row, xor row&7
    __shared__ __align__(16) unsigned short Ps[128 * 64];      // 16 KB [q][t], 8 chunks/row, xor row&7

    const int tid = threadIdx.x;
    const int lane = tid & 63;
    const int wave = tid >> 6;
    const int l32 = lane & 31;
    const int half = lane >> 5;

    // qi pairing: CU gets blocks y and y+8 (round-robin, 512 blocks / 256 CU)
    // -> qi {15-y, y}: per-CU tile count constant (34).
    const int yy = blockIdx.y;
    const int qi = (yy < 8) ? 15 - yy : yy - 8;
    const int bh = blockIdx.x;
    const int q0 = qi * 128;
    const int qg = q0 + wave * 32 + l32;        // this lane's global q row
    const int prow = wave * 32 + l32;           // P row (q local)
    const int psw = prow & 7;                   // P swizzle key

    const unsigned short* kb = k + (size_t)bh * Sd * Dd;
    const unsigned short* vtb = vt + (size_t)bh * Dd * Sd;

    // Q fragments straight from global: lane owns row qg, frag ks covers
    // d = ks*16 + half*8 + {0..7}  (B-operand layout), 8 x 16B loads.
    bf16x8 aq[8];
    {
        const unsigned short* qrow = q + ((size_t)bh * Sd + qg) * Dd;
#pragma unroll
        for (int ks = 0; ks < 8; ks++)
            aq[ks] = *(const bf16x8*)(qrow + ks * 16 + half * 8);
    }

    f32x16 o[4];   // O^T: d-block db: row d = db*32+(r&3)+8*(r>>2)+4*half, col q=l32
#pragma unroll
    for (int db = 0; db < 4; db++)
#pragma unroll
        for (int r = 0; r < 16; r++) o[db][r] = 0.f;
    float mi = -3.0e38f, li = 0.f;

    // stage K [64t][128d] and Vt [128d][64t] into buffer b, 1024 16B-chunks each
    auto stage = [&](int b, int t0) {
#pragma unroll
        for (int it = 0; it < 4; ++it) {
            int L = it * 256 + tid;
            int rk = L >> 4;
            int ck = L & 15;
            int gk = ck ^ (rk & 15);
            gl2lds16(kb + (size_t)(t0 + rk) * Dd + gk * 8,
                     (void*)(&Ks[b][0] + L * 8));
            int rv = L >> 3;
            int cv = L & 7;
            int gv = cv ^ (rv & 7);
            gl2lds16(vtb + (size_t)rv * Sd + t0 + gv * 8,
                     (void*)(&Vts[b][0] + L * 8));
        }
    };

    const int tmax = q0 + 64;
    stage(0, 0);
    int cur = 0;
    for (int t0 = 0; t0 <= tmax; t0 += 64) {
        __syncthreads();   // buf[cur] landed; prev iter's buf[cur^1] reads done
        if (t0 + 64 <= tmax) stage(cur ^ 1, t0 + 64);
        const unsigned short* Ksc = &Ks[cur][0];
        const unsigned short* Vtsc = &Vts[cur][0];

        // S^T = K * Q^T : 2 t-blocks of 32, contraction d=128 (8 ksteps)
        f32x16 sa[2];
#pragma unroll
        for (int b2 = 0; b2 < 2; b2++)
#pragma unroll
            for (int r = 0; r < 16; r++) sa[b2][r] = 0.f;
#pragma unroll
        for (int ks = 0; ks < 8; ks++) {
            int cd = ks * 2 + half;
#pragma unroll
            for (int b2 = 0; b2 < 2; b2++) {
                int row = b2 * 32 + l32;
                bf16x8 ak = *(const bf16x8*)(Ksc + row * 128 +
                                             (cd ^ (row & 15)) * 8);
                sa[b2] = __builtin_amdgcn_mfma_f32_32x32x16_bf16(ak, aq[ks],
                                                                 sa[b2], 0, 0, 0);
            }
        }

        // scale + causal mask; per-lane row max over 32 reg values + 1 shfl
        float mx = -3.0e38f;
#pragma unroll
        for (int b2 = 0; b2 < 2; b2++)
#pragma unroll
            for (int r = 0; r < 16; r++) {
                float v = sa[b2][r] * ATT_SCALE;
                int tg = t0 + b2 * 32 + (r & 3) + 8 * (r >> 2) + 4 * half;
                if (tg > qg) v = -3.0e38f;
                sa[b2][r] = v;
                mx = fmaxf(mx, v);
            }
        mx = fmaxf(mx, __shfl_xor(mx, 32, 64));
        const float mnew = fmaxf(mi, mx);
        const float alpha = __expf(mi - mnew);
        float rs = 0.f;
#pragma unroll
        for (int b2 = 0; b2 < 2; b2++)
#pragma unroll
            for (int r = 0; r < 16; r++) {
                float pp = __expf(sa[b2][r] - mnew);
                sa[b2][r] = pp;
                rs += pp;
            }
        rs += __shfl_xor(rs, 32, 64);
        li = li * alpha + rs;
        mi = mnew;

        // rescale O (fully in-lane: O^T col q == softmax lane q)
#pragma unroll
        for (int db = 0; db < 4; db++)
#pragma unroll
            for (int r = 0; r < 16; r++) o[db][r] *= alpha;

        // P store: row prow holds P[q][t] in t-order, 8 chunks of 8 ushorts,
        // chunk XOR-swizzled by prow&7. reg (b2,g) -> t = b2*32+8g+4*half+{0..3}
        // -> chunk b2*4+g, within-chunk half*4: 8B-aligned ds_write_b64.
        // P rows are wave-private: no barrier needed before the PV reads
        // (intra-wave ds ordering via lgkmcnt).
#pragma unroll
        for (int b2 = 0; b2 < 2; b2++)
#pragma unroll
            for (int g = 0; g < 4; g++) {
                ushort4 pk;
                pk.x = f2bf(sa[b2][g * 4 + 0]);
                pk.y = f2bf(sa[b2][g * 4 + 1]);
                pk.z = f2bf(sa[b2][g * 4 + 2]);
                pk.w = f2bf(sa[b2][g * 4 + 3]);
                *(ushort4*)(Ps + prow * 64 + ((b2 * 4 + g) ^ psw) * 8 +
                            half * 4) = pk;
            }

        // O^T += Vt * P^T : 4 d-blocks, contraction t=64 (4 ksteps)
        // bp chunk = kk*2+half -> t = kk*16+half*8+{0..7}: 16B-aligned b128.
#pragma unroll
        for (int kk = 0; kk < 4; kk++) {
            bf16x8 bp = *(const bf16x8*)(Ps + prow * 64 +
                                         ((kk * 2 + half) ^ psw) * 8);
#pragma unroll
            for (int db = 0; db < 4; db++) {
                int row = db * 32 + l32;
                bf16x8 av = *(const bf16x8*)(
                    Vtsc + row * 64 + ((kk * 2 + half) ^ (row & 7)) * 8);
                o[db] = __builtin_amdgcn_mfma_f32_32x32x16_bf16(av, bp, o[db],
                                                                0, 0, 0);
            }
        }
        cur ^= 1;
    }

    // epilogue: ctx[b, qg, h*128+d] = O^T[d][qg] / li  (bf16, ushort4 groups)
    const int b = bh >> 4;
    const int h = bh & 15;
    const float inv = 1.0f / li;
    unsigned short* dst = ctx + ((size_t)(b * Sd + qg)) * Ed + h * Dd;
#pragma unroll
    for (int db = 0; db < 4; db++)
#pragma unroll
        for (int g = 0; g < 4; g++) {
            ushort4 pk;
            pk.x = f2bf(o[db][g * 4 + 0] * inv);
            pk.y = f2bf(o[db][g * 4 + 1] * inv);
            pk.z = f2bf(o[db][g * 4 + 2] * inv);
            pk.w = f2bf(o[db][g * 4 + 3] * inv);
            *(ushort4*)(dst + db * 32 + g * 8 + half * 4) = pk;
        }
}

extern "C" void kernel_launch(void* const* d_in, const int* in_sizes, int n_in,
                              void* d_out, int out_size, void* d_ws,
                              size_t ws_size, hipStream_t stream) {
    const float* x = (const float*)d_in[0];
    const float* wqkv_w = (const float*)d_in[1];
    const float* wqkv_b = (const float*)d_in[2];
    const float* out_w = (const float*)d_in[3];
    const float* out_b = (const float*)d_in[4];
    float* out = (float*)d_out;

    // workspace layout (bytes); total 100,663,296 (96 MiB)
    char* ws = (char*)d_ws;
    unsigned short* xb    = (unsigned short*)(ws + 0);         // 16 MiB, dead after QKV GEMM
    unsigned short* wqkvb = (unsigned short*)(ws + 16777216);  // 24 MiB
    unsigned short* owb   = (unsigned short*)(ws + 41943040);  // 8 MiB
    unsigned short* qb    = (unsigned short*)(ws + 50331648);  // 16 MiB [B,H,S,D]
    unsigned short* kb    = (unsigned short*)(ws + 67108864);  // 16 MiB [B,H,S,D]
    unsigned short* vtb   = (unsigned short*)(ws + 83886080);  // 16 MiB [B,H,D,S]
    unsigned short* ctx   = (unsigned short*)(ws + 0);         // alias xb (dead)

    cvt_all<<<24576, 256, 0, stream>>>(x, wqkv_w, out_w, xb, wqkvb, owb);
    // qkv = x @ wqkv_w^T + b, fused RoPE (q,k) + V-transpose in epilogue
    gemm_bt<1><<<dim3(48, 32), 256, 0, stream>>>(xb, wqkvb, wqkv_b, qb, kb, vtb,
                                                 N3E, Ed);
    flash_attn<<<dim3(32, 16), 256, 0, stream>>>(qb, kb, vtb, ctx);
    // out = ctx @ out_w^T + b  (fp32)
    gemm_bt<0><<<dim3(16, 32), 256, 0, stream>>>(ctx, owb, out_b, out, nullptr,
                                                 nullptr, Ed, Ed);
}